// Round 1
// baseline (507.822 us; speedup 1.0000x reference)
//
#include <hip/hip_runtime.h>

// MultiHeadedAttention: B=4, S=2048, H=16, D_MODEL=1024, D_K=64
// Softmax over the QUERY axis (per key-column normalization).
// Pipeline: wprep -> proj_gemm(QKV, z=0..2) -> colsum -> attnpv -> out_gemm
// All heavy math in bf16 MFMA 16x16x32, fp32 accumulate.

#define DEV __device__ __forceinline__

typedef __bf16 bf16x8 __attribute__((ext_vector_type(8)));
typedef float  f32x4  __attribute__((ext_vector_type(4)));

DEV unsigned short f2bf(float f) {
    __bf16 h = (__bf16)f;
    return __builtin_bit_cast(unsigned short, h);
}

DEV bf16x8 ldfrag(const unsigned short* p) {
    return *reinterpret_cast<const bf16x8*>(p);
}

DEV void cvt8_store(unsigned short* dst, float4 a, float4 b) {
    bf16x8 v;
    v[0]=(__bf16)a.x; v[1]=(__bf16)a.y; v[2]=(__bf16)a.z; v[3]=(__bf16)a.w;
    v[4]=(__bf16)b.x; v[5]=(__bf16)b.y; v[6]=(__bf16)b.z; v[7]=(__bf16)b.w;
    *reinterpret_cast<bf16x8*>(dst) = v;
}

#define MFMA(a,b,c) __builtin_amdgcn_mfma_f32_16x16x32_bf16((a),(b),(c),0,0,0)

// ---------------------------------------------------------------------------
// Weight prep: Wq/Wk/Wv [16,1024,64] f32 -> Wt[z][n=h*64+k][m] bf16 (B^T layout)
//              Wo [1024,1024] f32 -> bf16 (already [n][m])
// ---------------------------------------------------------------------------
__global__ __launch_bounds__(256) void wprep(const float* __restrict__ Wq,
                                             const float* __restrict__ Wk,
                                             const float* __restrict__ Wv,
                                             const float* __restrict__ Wo,
                                             unsigned short* __restrict__ Wt,
                                             unsigned short* __restrict__ Wot) {
    int idx = blockIdx.x * 256 + threadIdx.x;   // < 1024*1024
    int which = blockIdx.y;
    if (which == 3) { Wot[idx] = f2bf(Wo[idx]); return; }
    const float* W = (which == 0) ? Wq : (which == 1) ? Wk : Wv;
    int n = idx >> 10, m = idx & 1023;
    int h = n >> 6, k = n & 63;
    Wt[(size_t)which * 1048576 + idx] = f2bf(W[h * 65536 + m * 64 + k]);
}

// ---------------------------------------------------------------------------
// Projection GEMM: C[8192 x 1024] = X(f32->bf16) * Wt^T + bias
// z=0 -> Qh[b,h,s,k] bf16 ; z=1 -> Kh[b,h,s,k] ; z=2 -> Vt[b,h,k,s] (transposed)
// Tile 128x128, BK=32, 256 thr (4 waves, 2x2), acc 4x4 frags/wave.
// ---------------------------------------------------------------------------
__global__ __launch_bounds__(256) void proj_gemm(
        const float* __restrict__ Xq, const float* __restrict__ Xk,
        const float* __restrict__ Xv, const unsigned short* __restrict__ Wt,
        const float* __restrict__ bq, const float* __restrict__ bk,
        const float* __restrict__ bv,
        unsigned short* __restrict__ Qh, unsigned short* __restrict__ Kh,
        unsigned short* __restrict__ Vt) {
    const int tid = threadIdx.x;
    const int bm = blockIdx.x, bn = blockIdx.y, z = blockIdx.z;
    const float* X = (z == 0) ? Xq : (z == 1) ? Xk : Xv;
    const unsigned short* Bt = Wt + (size_t)z * 1048576;
    const float* bias = (z == 0) ? bq : (z == 1) ? bk : bv;

    __shared__ __align__(16) unsigned short As[128 * 40];  // data 32, pad->40 (2-way banks)
    __shared__ __align__(16) unsigned short Bs[128 * 40];

    const int lane = tid & 63, wid = tid >> 6;
    const int l16 = lane & 15, quad = lane >> 4;
    const int wm = wid & 1, wn = wid >> 1;

    f32x4 acc[4][4] = {};

    for (int kt = 0; kt < 32; ++kt) {
        __syncthreads();
        const int k0 = kt * 32;
#pragma unroll
        for (int i = 0; i < 2; ++i) {
            int seg = tid + i * 256;          // 512 segs of 8 elems
            int row = seg >> 2, s4 = seg & 3;
            const float* gp = X + (size_t)(bm * 128 + row) * 1024 + k0 + s4 * 8;
            float4 f0 = *(const float4*)gp;
            float4 f1 = *(const float4*)(gp + 4);
            cvt8_store(&As[row * 40 + s4 * 8], f0, f1);
            const unsigned short* bp = Bt + (size_t)(bn * 128 + row) * 1024 + k0 + s4 * 8;
            *(uint4*)&Bs[row * 40 + s4 * 8] = *(const uint4*)bp;
        }
        __syncthreads();
        bf16x8 af[4], bfr[4];
#pragma unroll
        for (int mi = 0; mi < 4; ++mi)
            af[mi] = ldfrag(&As[(wm * 64 + mi * 16 + l16) * 40 + quad * 8]);
#pragma unroll
        for (int ni = 0; ni < 4; ++ni)
            bfr[ni] = ldfrag(&Bs[(wn * 64 + ni * 16 + l16) * 40 + quad * 8]);
#pragma unroll
        for (int mi = 0; mi < 4; ++mi)
#pragma unroll
            for (int ni = 0; ni < 4; ++ni)
                acc[mi][ni] = MFMA(af[mi], bfr[ni], acc[mi][ni]);
    }

#pragma unroll
    for (int mi = 0; mi < 4; ++mi)
#pragma unroll
        for (int ni = 0; ni < 4; ++ni)
#pragma unroll
            for (int r = 0; r < 4; ++r) {
                int row = bm * 128 + wm * 64 + mi * 16 + quad * 4 + r;  // flat b*s
                int col = bn * 128 + wn * 64 + ni * 16 + l16;           // h*64+k
                float v = acc[mi][ni][r] + bias[col];
                int b = row >> 11, s = row & 2047;
                int h = col >> 6, k = col & 63;
                unsigned short o = f2bf(v);
                if (z == 2) {
                    Vt[(size_t)((b * 16 + h) * 64 + k) * 2048 + s] = o;
                } else {
                    unsigned short* O = (z == 0) ? Qh : Kh;
                    O[(size_t)((b * 16 + h) * 2048 + s) * 64 + k] = o;
                }
            }
}

// ---------------------------------------------------------------------------
// Column softmax denominators: Dcol[b,h,s] = sum_q exp(scores[q,s])
// (scores bounded ~|2|: no max subtraction needed in fp32)
// Block owns 128 s-columns of one (b,h); loops all q in 128-row tiles.
// ---------------------------------------------------------------------------
__global__ __launch_bounds__(256) void colsum(const unsigned short* __restrict__ Qh,
                                              const unsigned short* __restrict__ Kh,
                                              float* __restrict__ Dcol) {
    const int tid = threadIdx.x;
    const int st = blockIdx.x, bh = blockIdx.y;
    const unsigned short* Qb = Qh + (size_t)bh * 2048 * 64;
    const unsigned short* Kb = Kh + (size_t)bh * 2048 * 64;

    __shared__ __align__(16) unsigned short Ks[128 * 72];  // data 64, pad->72
    __shared__ __align__(16) unsigned short Qs[128 * 72];
    __shared__ float Dtmp[2][128];

    const int lane = tid & 63, wid = tid >> 6;
    const int l16 = lane & 15, quad = lane >> 4;
    const int wm = wid & 1, wn = wid >> 1;

#pragma unroll
    for (int i = 0; i < 4; ++i) {              // stage K tile once (128x64)
        int seg = tid + i * 256;
        int row = seg >> 3, sc = seg & 7;
        *(uint4*)&Ks[row * 72 + sc * 8] =
            *(const uint4*)&Kb[(size_t)(st * 128 + row) * 64 + sc * 8];
    }

    float psum[4] = {0.f, 0.f, 0.f, 0.f};
    for (int q0 = 0; q0 < 2048; q0 += 128) {
        __syncthreads();
#pragma unroll
        for (int i = 0; i < 4; ++i) {
            int seg = tid + i * 256;
            int row = seg >> 3, sc = seg & 7;
            *(uint4*)&Qs[row * 72 + sc * 8] =
                *(const uint4*)&Qb[(size_t)(q0 + row) * 64 + sc * 8];
        }
        __syncthreads();
        f32x4 acc[4][4] = {};
#pragma unroll
        for (int ks = 0; ks < 2; ++ks) {
            bf16x8 af[4], bfr[4];
#pragma unroll
            for (int mi = 0; mi < 4; ++mi)
                af[mi] = ldfrag(&Qs[(wm * 64 + mi * 16 + l16) * 72 + ks * 32 + quad * 8]);
#pragma unroll
            for (int ni = 0; ni < 4; ++ni)
                bfr[ni] = ldfrag(&Ks[(wn * 64 + ni * 16 + l16) * 72 + ks * 32 + quad * 8]);
#pragma unroll
            for (int mi = 0; mi < 4; ++mi)
#pragma unroll
                for (int ni = 0; ni < 4; ++ni)
                    acc[mi][ni] = MFMA(af[mi], bfr[ni], acc[mi][ni]);
        }
#pragma unroll
        for (int ni = 0; ni < 4; ++ni) {
            float d = 0.f;
#pragma unroll
            for (int mi = 0; mi < 4; ++mi)
#pragma unroll
                for (int r = 0; r < 4; ++r)
                    d += __expf(acc[mi][ni][r] * 0.125f);
            psum[ni] += d;
        }
    }
#pragma unroll
    for (int ni = 0; ni < 4; ++ni) {           // reduce over quad groups (rows)
        float v = psum[ni];
        v += __shfl_xor(v, 16, 64);
        v += __shfl_xor(v, 32, 64);
        if (quad == 0) Dtmp[wm][wn * 64 + ni * 16 + l16] = v;
    }
    __syncthreads();
    if (tid < 128)
        Dcol[(size_t)bh * 2048 + st * 128 + tid] = Dtmp[0][tid] + Dtmp[1][tid];
}

// ---------------------------------------------------------------------------
// attn*V: Ctx[b,s,h*64+k] = sum_s' (exp(score)/Dcol[s']) * V[s',k]
// Block owns 128 q-rows of one (b,h); loops s in 64-col tiles.
// P goes D-layout -> LDS -> A-layout (verified m120 pattern).
// ---------------------------------------------------------------------------
__global__ __launch_bounds__(256) void attnpv(const unsigned short* __restrict__ Qh,
                                              const unsigned short* __restrict__ Kh,
                                              const unsigned short* __restrict__ Vtg,
                                              const float* __restrict__ Dcol,
                                              unsigned short* __restrict__ Ctx) {
    const int tid = threadIdx.x;
    const int qt = blockIdx.x, bh = blockIdx.y;
    const int b = bh >> 4, h = bh & 15;
    const unsigned short* Qb = Qh + (size_t)bh * 2048 * 64;
    const unsigned short* Kb = Kh + (size_t)bh * 2048 * 64;
    const unsigned short* Vb = Vtg + (size_t)bh * 64 * 2048;
    const float* Db = Dcol + (size_t)bh * 2048;

    __shared__ __align__(16) unsigned short Qs[128 * 72];
    __shared__ __align__(16) unsigned short Ks[64 * 72];
    __shared__ __align__(16) unsigned short Vs[64 * 72];   // [k][s] (B^T for PV)
    __shared__ __align__(16) unsigned short Ps[128 * 72];  // [q][s]
    __shared__ float Dinv[64];

    const int lane = tid & 63, wid = tid >> 6;
    const int l16 = lane & 15, quad = lane >> 4;
    const int wm = wid & 1, wn = wid >> 1;

#pragma unroll
    for (int i = 0; i < 4; ++i) {              // stage Q tile once (128x64)
        int seg = tid + i * 256;
        int row = seg >> 3, sc = seg & 7;
        *(uint4*)&Qs[row * 72 + sc * 8] =
            *(const uint4*)&Qb[(size_t)(qt * 128 + row) * 64 + sc * 8];
    }

    f32x4 cacc[2][4] = {};
    for (int s0 = 0; s0 < 2048; s0 += 64) {
        __syncthreads();
#pragma unroll
        for (int i = 0; i < 2; ++i) {          // stage K (64 s x 64 k) and V^T (64 k x 64 s)
            int seg = tid + i * 256;
            int row = seg >> 3, sc = seg & 7;
            *(uint4*)&Ks[row * 72 + sc * 8] =
                *(const uint4*)&Kb[(size_t)(s0 + row) * 64 + sc * 8];
            *(uint4*)&Vs[row * 72 + sc * 8] =
                *(const uint4*)&Vb[(size_t)row * 2048 + s0 + sc * 8];
        }
        if (tid < 64) Dinv[tid] = 1.0f / Db[s0 + tid];
        __syncthreads();

        // phase 1: scores (128q x 64s), waves 2x2 -> 64q x 32s each
        f32x4 sacc[4][2] = {};
#pragma unroll
        for (int ks = 0; ks < 2; ++ks) {
            bf16x8 af[4], bfr[2];
#pragma unroll
            for (int mi = 0; mi < 4; ++mi)
                af[mi] = ldfrag(&Qs[(wm * 64 + mi * 16 + l16) * 72 + ks * 32 + quad * 8]);
#pragma unroll
            for (int nj = 0; nj < 2; ++nj)
                bfr[nj] = ldfrag(&Ks[(wn * 32 + nj * 16 + l16) * 72 + ks * 32 + quad * 8]);
#pragma unroll
            for (int mi = 0; mi < 4; ++mi)
#pragma unroll
                for (int nj = 0; nj < 2; ++nj)
                    sacc[mi][nj] = MFMA(af[mi], bfr[nj], sacc[mi][nj]);
        }
#pragma unroll
        for (int mi = 0; mi < 4; ++mi)
#pragma unroll
            for (int nj = 0; nj < 2; ++nj) {
                int scol = wn * 32 + nj * 16 + l16;
                float dinv = Dinv[scol];
#pragma unroll
                for (int r = 0; r < 4; ++r) {
                    int qrow = wm * 64 + mi * 16 + quad * 4 + r;
                    Ps[qrow * 72 + scol] = f2bf(__expf(sacc[mi][nj][r] * 0.125f) * dinv);
                }
            }
        __syncthreads();

        // phase 2: ctx += P * V   (waves split 128q into 32-row strips)
#pragma unroll
        for (int ks2 = 0; ks2 < 2; ++ks2) {
            bf16x8 pa[2], vbf[4];
#pragma unroll
            for (int mi = 0; mi < 2; ++mi)
                pa[mi] = ldfrag(&Ps[(wid * 32 + mi * 16 + l16) * 72 + ks2 * 32 + quad * 8]);
#pragma unroll
            for (int ni = 0; ni < 4; ++ni)
                vbf[ni] = ldfrag(&Vs[(ni * 16 + l16) * 72 + ks2 * 32 + quad * 8]);
#pragma unroll
            for (int mi = 0; mi < 2; ++mi)
#pragma unroll
                for (int ni = 0; ni < 4; ++ni)
                    cacc[mi][ni] = MFMA(pa[mi], vbf[ni], cacc[mi][ni]);
        }
    }

#pragma unroll
    for (int mi = 0; mi < 2; ++mi)
#pragma unroll
        for (int ni = 0; ni < 4; ++ni)
#pragma unroll
            for (int r = 0; r < 4; ++r) {
                int q = qt * 128 + wid * 32 + mi * 16 + quad * 4 + r;
                int dk = ni * 16 + l16;
                Ctx[(size_t)(b * 2048 + q) * 1024 + h * 64 + dk] = f2bf(cacc[mi][ni][r]);
            }
}

// ---------------------------------------------------------------------------
// Output GEMM: Out[8192 x 1024] f32 = Ctx(bf16) * Wo^T + bo
// ---------------------------------------------------------------------------
__global__ __launch_bounds__(256) void out_gemm(const unsigned short* __restrict__ A,
                                                const unsigned short* __restrict__ Bt,
                                                const float* __restrict__ bias,
                                                float* __restrict__ Out) {
    const int tid = threadIdx.x;
    const int bm = blockIdx.x, bn = blockIdx.y;

    __shared__ __align__(16) unsigned short As[128 * 40];
    __shared__ __align__(16) unsigned short Bs[128 * 40];

    const int lane = tid & 63, wid = tid >> 6;
    const int l16 = lane & 15, quad = lane >> 4;
    const int wm = wid & 1, wn = wid >> 1;

    f32x4 acc[4][4] = {};
    for (int kt = 0; kt < 32; ++kt) {
        __syncthreads();
        const int k0 = kt * 32;
#pragma unroll
        for (int i = 0; i < 2; ++i) {
            int seg = tid + i * 256;
            int row = seg >> 2, s4 = seg & 3;
            *(uint4*)&As[row * 40 + s4 * 8] =
                *(const uint4*)&A[(size_t)(bm * 128 + row) * 1024 + k0 + s4 * 8];
            *(uint4*)&Bs[row * 40 + s4 * 8] =
                *(const uint4*)&Bt[(size_t)(bn * 128 + row) * 1024 + k0 + s4 * 8];
        }
        __syncthreads();
        bf16x8 af[4], bfr[4];
#pragma unroll
        for (int mi = 0; mi < 4; ++mi)
            af[mi] = ldfrag(&As[(wm * 64 + mi * 16 + l16) * 40 + quad * 8]);
#pragma unroll
        for (int ni = 0; ni < 4; ++ni)
            bfr[ni] = ldfrag(&Bs[(wn * 64 + ni * 16 + l16) * 40 + quad * 8]);
#pragma unroll
        for (int mi = 0; mi < 4; ++mi)
#pragma unroll
            for (int ni = 0; ni < 4; ++ni)
                acc[mi][ni] = MFMA(af[mi], bfr[ni], acc[mi][ni]);
    }
#pragma unroll
    for (int mi = 0; mi < 4; ++mi)
#pragma unroll
        for (int ni = 0; ni < 4; ++ni)
#pragma unroll
            for (int r = 0; r < 4; ++r) {
                int row = bm * 128 + wm * 64 + mi * 16 + quad * 4 + r;
                int col = bn * 128 + wn * 64 + ni * 16 + l16;
                Out[(size_t)row * 1024 + col] = acc[mi][ni][r] + bias[col];
            }
}

// ---------------------------------------------------------------------------
extern "C" void kernel_launch(void* const* d_in, const int* in_sizes, int n_in,
                              void* d_out, int out_size, void* d_ws, size_t ws_size,
                              hipStream_t stream) {
    (void)in_sizes; (void)n_in; (void)out_size; (void)ws_size;
    const float* query = (const float*)d_in[0];
    const float* key_  = (const float*)d_in[1];
    const float* value = (const float*)d_in[2];
    const float* Wq    = (const float*)d_in[3];
    const float* bq    = (const float*)d_in[4];
    const float* Wk    = (const float*)d_in[5];
    const float* bk    = (const float*)d_in[6];
    const float* Wv    = (const float*)d_in[7];
    const float* bv    = (const float*)d_in[8];
    const float* Wo    = (const float*)d_in[9];
    const float* bo    = (const float*)d_in[10];
    float* Out = (float*)d_out;

    char* ws = (char*)d_ws;
    const size_t MB = 1024 * 1024;
    unsigned short* Wt   = (unsigned short*)(ws);             // 6 MB  [3][1024][1024] bf16
    unsigned short* Wot  = (unsigned short*)(ws + 6 * MB);    // 2 MB
    unsigned short* Qh   = (unsigned short*)(ws + 8 * MB);    // 16 MB [b,h,s,64]
    unsigned short* Kh   = (unsigned short*)(ws + 24 * MB);   // 16 MB
    unsigned short* Vt   = (unsigned short*)(ws + 40 * MB);   // 16 MB [b,h,64,s]
    unsigned short* Ctx  = (unsigned short*)(ws + 56 * MB);   // 16 MB [b*s,1024]
    float* Dcol          = (float*)(ws + 72 * MB);            // 0.5 MB [b,h,s]

    wprep<<<dim3(4096, 4), dim3(256), 0, stream>>>(Wq, Wk, Wv, Wo, Wt, Wot);
    proj_gemm<<<dim3(64, 8, 3), dim3(256), 0, stream>>>(query, key_, value, Wt,
                                                        bq, bk, bv, Qh, Kh, Vt);
    colsum<<<dim3(16, 64), dim3(256), 0, stream>>>(Qh, Kh, Dcol);
    attnpv<<<dim3(16, 64), dim3(256), 0, stream>>>(Qh, Kh, Vt, Dcol, Ctx);
    out_gemm<<<dim3(64, 8), dim3(256), 0, stream>>>(Ctx, Wot, bo, Out);
}